// Round 1
// baseline (141.910 us; speedup 1.0000x reference)
//
#include <hip/hip_runtime.h>
#include <math.h>

#define N_CH 128
#define NB_MAX 512          // max bucket count (n_nodes <= 16384 -> nb <= 512)
#define BIN_CHUNK 2048
#define BIN_T 512

// ---------------------------------------------------------------------------
// K0: V1t[k*128+o] = W[o][k] - W[o][128+k], V2t[k*128+o] = W[o][128+k];
//     zero bucket histogram.
// ---------------------------------------------------------------------------
__global__ __launch_bounds__(256) void prep_kernel(const float* __restrict__ W,
                                                   float* __restrict__ V1,
                                                   float* __restrict__ V2,
                                                   int* __restrict__ binCount,
                                                   int nb) {
    int i = blockIdx.x * 256 + threadIdx.x;
    if (i < N_CH * N_CH) {
        int k = i >> 7, o = i & 127;
        float w1 = W[o * 256 + k];
        float w2 = W[o * 256 + 128 + k];
        V1[i] = w1 - w2;
        V2[i] = w2;
    }
    if (i < nb) binCount[i] = 0;
}

// ---------------------------------------------------------------------------
// K1: A = x @ V1 + bias (fp32), Bh = bf16(x @ V2). fp32 VALU GEMM.
// ---------------------------------------------------------------------------
__global__ __launch_bounds__(256) void gemm_kernel(const float* __restrict__ x,
                                                   const float* __restrict__ V1,
                                                   const float* __restrict__ V2,
                                                   const float* __restrict__ bias,
                                                   float* __restrict__ A,
                                                   unsigned short* __restrict__ Bh,
                                                   int n_nodes) {
    __shared__ float xs[32][N_CH];      // 16 KB
    const int n0 = blockIdx.x * 32;
    const int tid = threadIdx.x;

    if (n0 + 32 <= n_nodes) {
        const float4* xg = (const float4*)(x + (size_t)n0 * N_CH);
        float4* xsv = (float4*)&xs[0][0];
        #pragma unroll
        for (int i = 0; i < 4; ++i) xsv[tid + i * 256] = xg[tid + i * 256];
    } else {
        for (int i = tid; i < 32 * N_CH; i += 256) {
            int n = n0 + (i >> 7);
            (&xs[0][0])[i] = (n < n_nodes) ? x[(size_t)n * N_CH + (i & 127)] : 0.f;
        }
    }
    __syncthreads();

    const int o  = tid & 127;
    const int nh = tid >> 7;            // 0 or 1
    const float bo = bias[o];
    float acc1[16], acc2[16];
    #pragma unroll
    for (int i = 0; i < 16; ++i) { acc1[i] = 0.f; acc2[i] = 0.f; }

    const float* xrow = &xs[nh * 16][0];
    for (int k4 = 0; k4 < N_CH; k4 += 4) {
        float w1[4], w2[4];
        #pragma unroll
        for (int j = 0; j < 4; ++j) {
            w1[j] = V1[(k4 + j) * N_CH + o];
            w2[j] = V2[(k4 + j) * N_CH + o];
        }
        #pragma unroll
        for (int i = 0; i < 16; ++i) {
            float4 xv = *(const float4*)&xrow[i * N_CH + k4];
            acc1[i] = fmaf(xv.x, w1[0], acc1[i]); acc2[i] = fmaf(xv.x, w2[0], acc2[i]);
            acc1[i] = fmaf(xv.y, w1[1], acc1[i]); acc2[i] = fmaf(xv.y, w2[1], acc2[i]);
            acc1[i] = fmaf(xv.z, w1[2], acc1[i]); acc2[i] = fmaf(xv.z, w2[2], acc2[i]);
            acc1[i] = fmaf(xv.w, w1[3], acc1[i]); acc2[i] = fmaf(xv.w, w2[3], acc2[i]);
        }
    }

    #pragma unroll
    for (int i = 0; i < 16; ++i) {
        int n = n0 + nh * 16 + i;
        if (n < n_nodes) {
            A[(size_t)n * N_CH + o] = acc1[i] + bo;
            // bf16 round-to-nearest-even
            unsigned int bits = __float_as_uint(acc2[i]);
            unsigned int r = (bits + 0x7FFFu + ((bits >> 16) & 1u)) >> 16;
            Bh[(size_t)n * N_CH + o] = (unsigned short)r;
        }
    }
}

// ---------------------------------------------------------------------------
// K2: bucket histogram (bucket = dst >> 5). LDS-staged.
// ---------------------------------------------------------------------------
__global__ __launch_bounds__(256) void bhist_kernel(const int* __restrict__ dst,
                                                    int* __restrict__ binCount,
                                                    int n_edges, int nb) {
    __shared__ int h[NB_MAX];
    const int tid = threadIdx.x;
    for (int i = tid; i < nb; i += 256) h[i] = 0;
    __syncthreads();
    const int base = blockIdx.x * BIN_CHUNK;
    const int cnt = min(BIN_CHUNK, n_edges - base);
    for (int j = tid; j < cnt; j += 256)
        atomicAdd(&h[dst[base + j] >> 5], 1);
    __syncthreads();
    for (int i = tid; i < nb; i += 256)
        if (h[i]) atomicAdd(&binCount[i], h[i]);
}

// ---------------------------------------------------------------------------
// K3: exclusive scan over nb (<=512) bucket counts -> binOff[nb+1], binCursor
// ---------------------------------------------------------------------------
__global__ __launch_bounds__(512) void bscan_kernel(const int* __restrict__ binCount,
                                                    int* __restrict__ binOff,
                                                    int* __restrict__ binCursor,
                                                    int nb) {
    __shared__ int t[512];
    const int tid = threadIdx.x;
    int v = (tid < nb) ? binCount[tid] : 0;
    t[tid] = v;
    __syncthreads();
    #pragma unroll
    for (int off = 1; off < 512; off <<= 1) {
        int u = (tid >= off) ? t[tid - off] : 0;
        __syncthreads();
        t[tid] += u;
        __syncthreads();
    }
    if (tid < nb) {
        int excl = t[tid] - v;
        binOff[tid] = excl;
        binCursor[tid] = excl;
    }
    if (tid == 0) binOff[nb] = t[nb - 1];
}

// ---------------------------------------------------------------------------
// K4: bin scatter. Counting-sort BIN_CHUNK edges by bucket in LDS, reserve
// per-bucket global ranges, write packed (dst&31)<<14 | src in ordered runs.
// Requires n_nodes < 16384.
// ---------------------------------------------------------------------------
__global__ __launch_bounds__(BIN_T) void bin_kernel(const int* __restrict__ src,
                                                    const int* __restrict__ dst,
                                                    int* __restrict__ binCursor,
                                                    unsigned int* __restrict__ binned,
                                                    int n_edges, int nb) {
    __shared__ unsigned int   lpk[BIN_CHUNK];      // 8 KB
    __shared__ unsigned short lbk[BIN_CHUNK];      // 4 KB
    __shared__ int sc[512];
    __shared__ int lhist[NB_MAX], lexcl[NB_MAX], lcur[NB_MAX], bbase[NB_MAX];

    const int tid = threadIdx.x;
    const int base = blockIdx.x * BIN_CHUNK;
    const int cnt = min(BIN_CHUNK, n_edges - base);

    for (int i = tid; i < nb; i += BIN_T) lhist[i] = 0;
    __syncthreads();

    unsigned int vreg[BIN_CHUNK / BIN_T];
    unsigned short breg[BIN_CHUNK / BIN_T];
    int nloc = 0;
    for (int j = tid; j < cnt; j += BIN_T) {
        int s = src[base + j];
        int d = dst[base + j];
        int b = d >> 5;
        vreg[nloc] = ((unsigned int)(d & 31) << 14) | (unsigned int)s;
        breg[nloc] = (unsigned short)b;
        ++nloc;
        atomicAdd(&lhist[b], 1);
    }
    __syncthreads();

    int v = (tid < nb) ? lhist[tid] : 0;
    sc[tid] = v;
    __syncthreads();
    #pragma unroll
    for (int off = 1; off < 512; off <<= 1) {
        int u = (tid >= off) ? sc[tid - off] : 0;
        __syncthreads();
        sc[tid] += u;
        __syncthreads();
    }
    if (tid < nb) {
        int excl = sc[tid] - v;
        lexcl[tid] = excl;
        lcur[tid] = excl;
    }
    __syncthreads();

    for (int k = 0; k < nloc; ++k) {
        int b = breg[k];
        int p = atomicAdd(&lcur[b], 1);
        lpk[p] = vreg[k];
        lbk[p] = (unsigned short)b;
    }
    __syncthreads();

    for (int b = tid; b < nb; b += BIN_T) {
        int c = lhist[b];
        if (c) bbase[b] = atomicAdd(&binCursor[b], c);
    }
    __syncthreads();

    for (int i = tid; i < cnt; i += BIN_T) {
        int b = lbk[i];
        binned[bbase[b] + (i - lexcl[b])] = lpk[i];
    }
}

// ---------------------------------------------------------------------------
// K5: per-bucket CSR build. One block per bucket (32 nodes): local hist/scan
// in LDS, eidx scatter confined to the bucket's contiguous window,
// global offsets[] emitted directly.
// ---------------------------------------------------------------------------
__global__ __launch_bounds__(256) void build_kernel(const unsigned int* __restrict__ binned,
                                                    const int* __restrict__ binOff,
                                                    int* __restrict__ offsets,
                                                    int* __restrict__ eidx,
                                                    int n_nodes, int nb) {
    __shared__ int lhist[32], lexcl[33], lcur[32];
    const int b = blockIdx.x;
    const int tid = threadIdx.x;
    const int rbeg = binOff[b], rend = binOff[b + 1];

    if (tid < 32) { lhist[tid] = 0; lcur[tid] = 0; }
    __syncthreads();
    for (int i = rbeg + tid; i < rend; i += 256)
        atomicAdd(&lhist[binned[i] >> 14], 1);
    __syncthreads();
    if (tid == 0) {
        int s = 0;
        for (int k = 0; k < 32; ++k) { lexcl[k] = s; s += lhist[k]; }
        lexcl[32] = s;
    }
    __syncthreads();
    if (tid < 32) {
        int n = b * 32 + tid;
        if (n < n_nodes) offsets[n] = rbeg + lexcl[tid];
    }
    if (b == nb - 1 && tid == 0) offsets[n_nodes] = rend;
    for (int i = rbeg + tid; i < rend; i += 256) {
        unsigned int w = binned[i];
        int d5 = (int)(w >> 14);
        int r = atomicAdd(&lcur[d5], 1);
        eidx[rbeg + lexcl[d5] + r] = (int)(w & 16383u);
    }
}

// ---------------------------------------------------------------------------
// K6: per-node gather-max. One WAVE (64 lanes) per node, 4 nodes per block.
// 16 lanes cover one 256 B Bh row (uint4 = 8 channels/lane); the 4 sub-groups
// of the wave cover 4 edges per load instruction (1 KB/instr), 4 loads in
// flight -> 64 B/lane outstanding. Edge order is irrelevant to max, so the
// sub-groups are merged at the end with a 2-step shfl_xor max-reduce.
// Wave-synchronous LDS index staging (single wave -> no __syncthreads).
// Epilogue: out = A' + max (bias pre-folded in A'); isolated nodes -> 0.
// ---------------------------------------------------------------------------
__global__ __launch_bounds__(256) void gather_kernel(
        const float* __restrict__ A,
        const uint4* __restrict__ Bh4,   // n_nodes x 16 uint4 (128 bf16)
        const int* __restrict__ offsets,
        const int* __restrict__ eidx,
        float* __restrict__ out,
        int n_nodes) {
    __shared__ int sidx[4][64];
    const int g = threadIdx.x >> 6;
    const int l = threadIdx.x & 63;
    const int n = blockIdx.x * 4 + g;
    if (n >= n_nodes) return;
    const int beg = offsets[n], end = offsets[n + 1];

    const int sub = l >> 4;   // which of 4 edges within a load group
    const int col = l & 15;   // 16 B column within the 256 B row

    float mlo[4][4], mhi[4][4];
    #pragma unroll
    for (int s = 0; s < 4; ++s)
        #pragma unroll
        for (int u = 0; u < 4; ++u) { mlo[s][u] = -INFINITY; mhi[s][u] = -INFINITY; }

    for (int base = beg; base < end; base += 64) {
        int p = base + l;
        if (p < end) sidx[g][l] = eidx[p];
        // single-wave lockstep: same-wave DS ordering makes the write visible
        int cnt = min(64, end - base);
        int q = 0;
        for (; q + 16 <= cnt; q += 16) {
            int e[4];
            #pragma unroll
            for (int s = 0; s < 4; ++s) e[s] = sidx[g][q + 4 * s + sub];
            uint4 w[4];
            #pragma unroll
            for (int s = 0; s < 4; ++s) w[s] = Bh4[(size_t)e[s] * 16 + col];
            #pragma unroll
            for (int s = 0; s < 4; ++s) {
                mlo[s][0] = fmaxf(mlo[s][0], __uint_as_float(w[s].x << 16));
                mhi[s][0] = fmaxf(mhi[s][0], __uint_as_float(w[s].x & 0xFFFF0000u));
                mlo[s][1] = fmaxf(mlo[s][1], __uint_as_float(w[s].y << 16));
                mhi[s][1] = fmaxf(mhi[s][1], __uint_as_float(w[s].y & 0xFFFF0000u));
                mlo[s][2] = fmaxf(mlo[s][2], __uint_as_float(w[s].z << 16));
                mhi[s][2] = fmaxf(mhi[s][2], __uint_as_float(w[s].z & 0xFFFF0000u));
                mlo[s][3] = fmaxf(mlo[s][3], __uint_as_float(w[s].w << 16));
                mhi[s][3] = fmaxf(mhi[s][3], __uint_as_float(w[s].w & 0xFFFF0000u));
            }
        }
        for (; q < cnt; q += 4) {
            int r = q + sub;
            if (r < cnt) {
                int e = sidx[g][r];
                uint4 w = Bh4[(size_t)e * 16 + col];
                mlo[0][0] = fmaxf(mlo[0][0], __uint_as_float(w.x << 16));
                mhi[0][0] = fmaxf(mhi[0][0], __uint_as_float(w.x & 0xFFFF0000u));
                mlo[0][1] = fmaxf(mlo[0][1], __uint_as_float(w.y << 16));
                mhi[0][1] = fmaxf(mhi[0][1], __uint_as_float(w.y & 0xFFFF0000u));
                mlo[0][2] = fmaxf(mlo[0][2], __uint_as_float(w.z << 16));
                mhi[0][2] = fmaxf(mhi[0][2], __uint_as_float(w.z & 0xFFFF0000u));
                mlo[0][3] = fmaxf(mlo[0][3], __uint_as_float(w.w << 16));
                mhi[0][3] = fmaxf(mhi[0][3], __uint_as_float(w.w & 0xFFFF0000u));
            }
        }
    }

    // merge the 4 load slots
    float lo[4], hi[4];
    #pragma unroll
    for (int u = 0; u < 4; ++u) {
        lo[u] = fmaxf(fmaxf(mlo[0][u], mlo[1][u]), fmaxf(mlo[2][u], mlo[3][u]));
        hi[u] = fmaxf(fmaxf(mhi[0][u], mhi[1][u]), fmaxf(mhi[2][u], mhi[3][u]));
    }
    // reduce across the 4 sub-groups (lanes sharing `col`)
    #pragma unroll
    for (int u = 0; u < 4; ++u) {
        lo[u] = fmaxf(lo[u], __shfl_xor(lo[u], 16, 64));
        hi[u] = fmaxf(hi[u], __shfl_xor(hi[u], 16, 64));
        lo[u] = fmaxf(lo[u], __shfl_xor(lo[u], 32, 64));
        hi[u] = fmaxf(hi[u], __shfl_xor(hi[u], 32, 64));
    }

    if (sub == 0) {
        // lane holds max for channels col*8 .. col*8+7 (lo=even, hi=odd)
        float r8[8];
        if (end > beg) {
            const float4* Arow = (const float4*)(A + (size_t)n * N_CH + col * 8);
            float4 a0 = Arow[0], a1 = Arow[1];
            r8[0] = a0.x + lo[0]; r8[1] = a0.y + hi[0];
            r8[2] = a0.z + lo[1]; r8[3] = a0.w + hi[1];
            r8[4] = a1.x + lo[2]; r8[5] = a1.y + hi[2];
            r8[6] = a1.z + lo[3]; r8[7] = a1.w + hi[3];
        } else {
            #pragma unroll
            for (int i = 0; i < 8; ++i) r8[i] = 0.f;
        }
        float4* orow = (float4*)(out + (size_t)n * N_CH + col * 8);
        orow[0] = make_float4(r8[0], r8[1], r8[2], r8[3]);
        orow[1] = make_float4(r8[4], r8[5], r8[6], r8[7]);
    }
}

// ---------------------------------------------------------------------------
extern "C" void kernel_launch(void* const* d_in, const int* in_sizes, int n_in,
                              void* d_out, int out_size, void* d_ws, size_t ws_size,
                              hipStream_t stream) {
    const float* x = (const float*)d_in[0];
    const float* W = (const float*)d_in[1];
    const float* b = (const float*)d_in[2];
    const int*   ei = (const int*)d_in[3];

    const int n_nodes = in_sizes[0] / N_CH;   // 10000
    const int n_edges = in_sizes[3] / 2;      // 640000
    const int nb = (n_nodes + 31) >> 5;       // 313 buckets of 32 nodes
    const int* src = ei;
    const int* dst = ei + n_edges;
    float* out = (float*)d_out;

    char* ws = (char*)d_ws;
    size_t off = 0;
    auto alloc = [&](size_t bytes) -> void* {
        void* p = ws + off;
        off += (bytes + 255) & ~(size_t)255;
        return p;
    };
    float* V1        = (float*)alloc((size_t)N_CH * N_CH * 4);
    float* V2        = (float*)alloc((size_t)N_CH * N_CH * 4);
    float* A         = (float*)alloc((size_t)n_nodes * N_CH * 4);
    unsigned short* Bh = (unsigned short*)alloc((size_t)n_nodes * N_CH * 2);
    int*   binCount  = (int*)alloc((size_t)nb * 4);
    int*   binOff    = (int*)alloc((size_t)(nb + 1) * 4);
    int*   binCursor = (int*)alloc((size_t)nb * 4);
    unsigned int* binned = (unsigned int*)alloc((size_t)n_edges * 4);
    int*   offsets   = (int*)alloc((size_t)(n_nodes + 1) * 4);
    int*   eidx      = (int*)alloc((size_t)n_edges * 4);
    (void)ws_size; (void)n_in; (void)out_size;

    const int nbin_blocks = (n_edges + BIN_CHUNK - 1) / BIN_CHUNK;

    prep_kernel <<<(N_CH * N_CH + 255) / 256, 256, 0, stream>>>(W, V1, V2, binCount, nb);
    gemm_kernel <<<(n_nodes + 31) / 32, 256, 0, stream>>>(x, V1, V2, b, A, Bh, n_nodes);
    bhist_kernel<<<nbin_blocks, 256, 0, stream>>>(dst, binCount, n_edges, nb);
    bscan_kernel<<<1, 512, 0, stream>>>(binCount, binOff, binCursor, nb);
    bin_kernel  <<<nbin_blocks, BIN_T, 0, stream>>>(src, dst, binCursor, binned, n_edges, nb);
    build_kernel<<<nb, 256, 0, stream>>>(binned, binOff, offsets, eidx, n_nodes, nb);
    gather_kernel<<<(n_nodes + 3) / 4, 256, 0, stream>>>(A, (const uint4*)Bh, offsets, eidx, out, n_nodes);
}